// Round 13
// baseline (305.871 us; speedup 1.0000x reference)
//
#include <hip/hip_runtime.h>
#include <hip/hip_bf16.h>

// Problem constants
#define NB 4
#define NC 256
#define ND 32
#define WH 1024          // W*H
#define DWH 32768        // D*W*H
#define KTOT 1024        // 4 modalities * 256 channels

typedef __attribute__((ext_vector_type(8))) short short8;
typedef __attribute__((ext_vector_type(4))) float f32x4;

static __device__ __forceinline__ unsigned short f32_to_bf16(float f) {
    unsigned u = __builtin_bit_cast(unsigned, f);
    u = u + 0x7fff + ((u >> 16) & 1);   // round-to-nearest-even
    return (unsigned short)(u >> 16);
}

// HW-packed convert: v_cvt_pk_bf16_f32 (1 instr per pair).
static __device__ __forceinline__ unsigned pack_bf16x2(float lo, float hi) {
    __hip_bfloat162 h = __float22bfloat162_rn(make_float2(lo, hi));
    unsigned u;
    __builtin_memcpy(&u, &h, 4);
    return u;
}

// ===========================================================================
// NEW PATH K1: fused pool + bf16 transcode into GEMM-tile layout.
// Grid (b,m,cb,d) = 2048 blocks. Each block: 64 channels x 1024 x (one d).
// Bt layout: tiles [b][xt(256)][kt(16)] of [xl(128)][k(64)] bf16, 16KB each,
// k-contiguous rows of 128B -> gemm stages via global_load_lds like A.
// Pool: per-c running sums during the coalesced read phase.
// ===========================================================================
__global__ __launch_bounds__(256) void transpool_kernel(
    const float* __restrict__ i0, const float* __restrict__ i1,
    const float* __restrict__ i2, const float* __restrict__ i3,
    unsigned short* __restrict__ Bt, float* __restrict__ pooled)
{
    __shared__ float lds[64 * 132];   // [c][x] fp32, pitch 132 floats (16B-mult)
    int bid = blockIdx.x;
    int d  = bid & 31;
    int cb = (bid >> 5) & 3;
    int m  = (bid >> 7) & 3;
    int b  = bid >> 9;
    const float* base = (m == 0 ? i0 : m == 1 ? i1 : m == 2 ? i2 : i3)
                        + ((size_t)(b * NC + cb * 64)) * DWH + d * WH;
    int t  = threadIdx.x;
    int rl = t >> 3;                 // row-local 0..31 (covers c=rl and c=32+rl)
    int xo = t & 7;                  // 16B slot within 128B group
    int xr = t >> 1;                 // transpose-read: x row 0..127
    int ch = t & 1;                  // transpose-read: k half (32 c's)

    float pc0 = 0.f, pc1 = 0.f;
    float4 v0[4], v1[4];

    // ---- prologue: load sub-chunk 0, accumulate, stage to LDS ----
    #pragma unroll
    for (int j = 0; j < 4; ++j) {
        v0[j] = *(const float4*)(base + (size_t)rl * DWH + (xo + 8 * j) * 4);
        v1[j] = *(const float4*)(base + (size_t)(32 + rl) * DWH + (xo + 8 * j) * 4);
    }
    #pragma unroll
    for (int j = 0; j < 4; ++j) {
        pc0 += v0[j].x + v0[j].y + v0[j].z + v0[j].w;
        pc1 += v1[j].x + v1[j].y + v1[j].z + v1[j].w;
        *(float4*)&lds[rl * 132 + (xo + 8 * j) * 4]        = v0[j];
        *(float4*)&lds[(32 + rl) * 132 + (xo + 8 * j) * 4] = v1[j];
    }
    __syncthreads();

    // tile base for s: tb0 + s*16*8192 (xt = d*8+s, kt = m*4+cb)
    unsigned short* tb0 = Bt + (((size_t)b * 256 + d * 8) * 16 + (m * 4 + cb)) * 8192;

    #pragma unroll 1
    for (int s = 0; s < 8; ++s) {
        if (s < 7) {   // issue loads for s+1 (consumed after next barrier)
            const float* bs = base + (s + 1) * 128;
            #pragma unroll
            for (int j = 0; j < 4; ++j) {
                v0[j] = *(const float4*)(bs + (size_t)rl * DWH + (xo + 8 * j) * 4);
                v1[j] = *(const float4*)(bs + (size_t)(32 + rl) * DWH + (xo + 8 * j) * 4);
            }
        }
        // ---- transpose-read chunk s, pack bf16, write tile (coalesced) ----
        {
            unsigned short* dst = tb0 + (size_t)s * 16 * 8192 + (size_t)xr * 64 + ch * 32;
            unsigned pk[16];
            #pragma unroll
            for (int i = 0; i < 16; ++i) {
                float f0 = lds[(ch * 32 + 2 * i) * 132 + xr];
                float f1 = lds[(ch * 32 + 2 * i + 1) * 132 + xr];
                pk[i] = pack_bf16x2(f0, f1);
            }
            #pragma unroll
            for (int u = 0; u < 4; ++u)
                *(uint4*)(dst + u * 8) =
                    (uint4){pk[4 * u], pk[4 * u + 1], pk[4 * u + 2], pk[4 * u + 3]};
        }
        __syncthreads();
        if (s < 7) {   // accumulate + stage s+1 into LDS
            #pragma unroll
            for (int j = 0; j < 4; ++j) {
                pc0 += v0[j].x + v0[j].y + v0[j].z + v0[j].w;
                pc1 += v1[j].x + v1[j].y + v1[j].z + v1[j].w;
                *(float4*)&lds[rl * 132 + (xo + 8 * j) * 4]        = v0[j];
                *(float4*)&lds[(32 + rl) * 132 + (xo + 8 * j) * 4] = v1[j];
            }
            __syncthreads();
        }
    }

    // ---- pool reduce over the 8 xo-lanes ----
    pc0 += __shfl_down(pc0, 4, 64); pc1 += __shfl_down(pc1, 4, 64);
    pc0 += __shfl_down(pc0, 2, 64); pc1 += __shfl_down(pc1, 2, 64);
    pc0 += __shfl_down(pc0, 1, 64); pc1 += __shfl_down(pc1, 1, 64);
    if (xo == 0) {
        pooled[((size_t)b * NC + cb * 64 + rl) * 128 + m * 32 + d]      = pc0 * (1.0f / 1024.0f);
        pooled[((size_t)b * NC + cb * 64 + 32 + rl) * 128 + m * 32 + d] = pc1 * (1.0f / 1024.0f);
    }
}

// ===========================================================================
// OLD PATH K1 (fallback): pool only.
// ===========================================================================
__global__ __launch_bounds__(256) void pool_kernel(
    const float* __restrict__ i0, const float* __restrict__ i1,
    const float* __restrict__ i2, const float* __restrict__ i3,
    float* __restrict__ pooled)
{
    int bid = blockIdx.x;            // (b*NC + c)*4 + m
    int m   = bid & 3;
    int bc  = bid >> 2;
    const float* src = (m == 0 ? i0 : m == 1 ? i1 : m == 2 ? i2 : i3)
                       + (size_t)bc * DWH;
    int t = threadIdx.x;
    int d   = t >> 3;
    int sub = t & 7;

    const float4* row = (const float4*)(src + (size_t)d * WH);
    float4 a0 = {0.f, 0.f, 0.f, 0.f}, a1 = {0.f, 0.f, 0.f, 0.f};
    #pragma unroll
    for (int j = 0; j < 16; ++j) {
        float4 u = row[sub + 8 * (2 * j)];
        float4 w = row[sub + 8 * (2 * j + 1)];
        a0.x += u.x; a0.y += u.y; a0.z += u.z; a0.w += u.w;
        a1.x += w.x; a1.y += w.y; a1.z += w.z; a1.w += w.w;
    }
    float s = (a0.x + a0.y) + (a0.z + a0.w) + (a1.x + a1.y) + (a1.z + a1.w);
    s += __shfl_down(s, 4, 64);
    s += __shfl_down(s, 2, 64);
    s += __shfl_down(s, 1, 64);
    if (sub == 0) pooled[bc * 128 + m * 32 + d] = s * (1.0f / 1024.0f);
}

// ---------------------------------------------------------------------------
// Kernel 2: attention weights + effective GEMM A-matrix + effective bias.
// ---------------------------------------------------------------------------
__global__ __launch_bounds__(64) void attn_kernel(
    const float* __restrict__ pooled,
    const float* __restrict__ Wq, const float* __restrict__ bq,
    const float* __restrict__ Wk, const float* __restrict__ bk,
    const float* __restrict__ Wc, const float* __restrict__ bcv,
    unsigned short* __restrict__ Amat, float* __restrict__ beff)
{
    int bc_idx = blockIdx.x;             // b*NC + c
    int lane = threadIdx.x;
    int e = lane & 31;
    const float* P = pooled + bc_idx * 128;

    float q = 0.f, kv[4] = {0.f, 0.f, 0.f, 0.f};
    for (int d = 0; d < 32; ++d) {
        float pq = P[d];
        float wq = Wq[e * 32 + d], wk = Wk[e * 32 + d];
        q += pq * wq;
        #pragma unroll
        for (int m = 0; m < 4; ++m) kv[m] += P[m * 32 + d] * wk;
    }
    q += bq[e];
    #pragma unroll
    for (int m = 0; m < 4; ++m) kv[m] += bk[e];

    float lg[4];
    #pragma unroll
    for (int m = 0; m < 4; ++m) {
        float p = q * kv[m];
        #pragma unroll
        for (int off = 16; off; off >>= 1) p += __shfl_xor(p, off, 32);
        lg[m] = p * 0.17677669529663687f;    // 1/sqrt(32)
    }
    float mx = fmaxf(fmaxf(lg[0], lg[1]), fmaxf(lg[2], lg[3]));
    float ex[4], s = 0.f;
    #pragma unroll
    for (int m = 0; m < 4; ++m) { ex[m] = __expf(lg[m] - mx); s += ex[m]; }
    float a[4];
    #pragma unroll
    for (int m = 0; m < 4; ++m) a[m] = ex[m] / s;

    int c = bc_idx & 255;
    if (lane == 0) {
        float be = 0.f;
        #pragma unroll
        for (int m = 0; m < 4; ++m) be += a[m] * bcv[m * NC + c];
        beff[bc_idx] = be;
    }
    unsigned short* Arow = Amat + (size_t)bc_idx * KTOT;
    #pragma unroll
    for (int j = 0; j < 16; ++j) {
        int k = j * 64 + lane;
        int m = k >> 8, cin = k & 255;
        float v = a[m] * Wc[(m * NC + c) * NC + cin];
        Arow[k] = f32_to_bf16(v);
    }
}

#define BM 128
#define BN 128
#define BK 64

static __device__ __forceinline__ int swzA(int row, int chunk) {
    // ushort units: row stride 64 ushorts (=128B), chunk = 8 ushorts (=16B)
    return row * 64 + ((chunk ^ (row & 7)) << 3);
}
static __device__ __forceinline__ int swzB(int row, int chunk) {
    return row * 64 + ((chunk ^ ((row >> 1) & 7)) << 3);
}

// ===========================================================================
// NEW PATH K3: all-bf16 GEMM. A and B both staged via global_load_lds
// (pre-swizzled per-lane source, linear LDS dest), both double-buffered one
// K-tile ahead; the only in-loop wait is the counted vmcnt(8).
// ===========================================================================
__global__ __launch_bounds__(256, 2) void gemm2_kernel(
    const unsigned short* __restrict__ Amat,
    const unsigned short* __restrict__ Bt,
    const float* __restrict__ beff,
    float* __restrict__ out)
{
    __shared__ __align__(16) short As[2 * BM * BK];   // 32KB dbuf
    __shared__ __align__(16) short Bs[2 * BN * BK];   // 32KB dbuf

    int raw = blockIdx.x;
    int sb  = (raw & 7) * 256 + (raw >> 3);
    int ot = sb & 1;
    int xt = (sb >> 1) & 255;
    int b  = sb >> 9;
    int o0 = ot * BM, x0 = xt * BN;

    int t = threadIdx.x;
    int wave = t >> 6, lane = t & 63;
    int wr = wave >> 1, wc = wave & 1;
    int lrow = lane & 15, lk = lane >> 4;
    int lr8 = lane >> 3;
    int aq  = (lane & 7) ^ lr8;

    const unsigned short* asrc = Amat + ((size_t)b * NC + o0) * KTOT
                                 + (size_t)(wave * 32 + lr8) * KTOT + aq * 8;
    const unsigned short* bsrc = Bt + ((size_t)b * 256 + xt) * 16 * 8192
                                 + (size_t)(wave * 32 + lr8) * 64 + aq * 8;

    f32x4 acc[4][4];
    #pragma unroll
    for (int mi = 0; mi < 4; ++mi)
        #pragma unroll
        for (int ni = 0; ni < 4; ++ni)
            acc[mi][ni] = (f32x4){0.f, 0.f, 0.f, 0.f};

    // ---- prologue: issue tile 0 into buf0 (8 vmem per wave) ----
    #pragma unroll
    for (int p = 0; p < 4; ++p)
        __builtin_amdgcn_global_load_lds(
            (const __attribute__((address_space(1))) unsigned int*)
                (asrc + (size_t)p * 8 * KTOT),
            (__attribute__((address_space(3))) unsigned int*)
                (As + (wave * 32 + p * 8) * 64), 16, 0, 0);
    #pragma unroll
    for (int p = 0; p < 4; ++p)
        __builtin_amdgcn_global_load_lds(
            (const __attribute__((address_space(1))) unsigned int*)
                (bsrc + (size_t)p * 8 * 64),
            (__attribute__((address_space(3))) unsigned int*)
                (Bs + (wave * 32 + p * 8) * 64), 16, 0, 0);
    __builtin_amdgcn_sched_barrier(0);

    #pragma unroll 1
    for (int it = 0; it < 16; ++it) {
        // ---- issue next tile -> buf^1 (8 vmem; last iter re-issues 15) ----
        int ja = (it < 15) ? it + 1 : 15;
        int bo = ((it + 1) & 1) * (BM * BK);
        #pragma unroll
        for (int p = 0; p < 4; ++p)
            __builtin_amdgcn_global_load_lds(
                (const __attribute__((address_space(1))) unsigned int*)
                    (asrc + (size_t)p * 8 * KTOT + ja * BK),
                (__attribute__((address_space(3))) unsigned int*)
                    (As + bo + (wave * 32 + p * 8) * 64), 16, 0, 0);
        #pragma unroll
        for (int p = 0; p < 4; ++p)
            __builtin_amdgcn_global_load_lds(
                (const __attribute__((address_space(1))) unsigned int*)
                    (bsrc + (size_t)ja * 8192 + p * 8 * 64),
                (__attribute__((address_space(3))) unsigned int*)
                    (Bs + bo + (wave * 32 + p * 8) * 64), 16, 0, 0);
        __builtin_amdgcn_sched_barrier(0);

        // ---- current tile's 8 loads landed (8 newer in flight) ----
        asm volatile("s_waitcnt vmcnt(8)" ::: "memory");
        __builtin_amdgcn_s_barrier();
        __builtin_amdgcn_sched_barrier(0);

        // ---- compute on buf cur ----
        const short* Acur = As + (it & 1) * (BM * BK);
        const short* Bcur = Bs + (it & 1) * (BM * BK);
        #pragma unroll
        for (int kk = 0; kk < 2; ++kk) {
            int q = kk * 4 + lk;
            short8 af[4], bf[4];
            #pragma unroll
            for (int mi = 0; mi < 4; ++mi)
                af[mi] = *(const short8*)(&Acur[swzA(wr * 64 + mi * 16 + lrow, q)]);
            #pragma unroll
            for (int ni = 0; ni < 4; ++ni)
                bf[ni] = *(const short8*)(&Bcur[swzA(wc * 64 + ni * 16 + lrow, q)]);
            __builtin_amdgcn_s_setprio(1);
            #pragma unroll
            for (int mi = 0; mi < 4; ++mi)
                #pragma unroll
                for (int ni = 0; ni < 4; ++ni)
                    acc[mi][ni] = __builtin_amdgcn_mfma_f32_16x16x32_bf16(
                        af[mi], bf[ni], acc[mi][ni], 0, 0, 0);
            __builtin_amdgcn_s_setprio(0);
        }
        // ---- all waves done reading buf cur (next iter overwrites it) ----
        __builtin_amdgcn_s_barrier();
        __builtin_amdgcn_sched_barrier(0);
    }

    // ---- epilogue ----
    const float* beff_b = beff + b * NC + o0;
    float* outb = out + ((size_t)b * NC + o0) * DWH + x0;
    #pragma unroll
    for (int mi = 0; mi < 4; ++mi) {
        #pragma unroll
        for (int r4 = 0; r4 < 4; ++r4) {
            int row = wr * 64 + mi * 16 + lk * 4 + r4;
            float bias = beff_b[row];
            float* orow = outb + (size_t)row * DWH;
            #pragma unroll
            for (int ni = 0; ni < 4; ++ni) {
                int col = wc * 64 + ni * 16 + lrow;
                orow[col] = acc[mi][ni][r4] + bias;
            }
        }
    }
}

// ===========================================================================
// OLD PATH K3 (fallback): R12 gemm (fp32 B reg-staged + cvt_pk).
// ===========================================================================
__global__ __launch_bounds__(256, 3) void gemm_kernel(
    const float* __restrict__ i0, const float* __restrict__ i1,
    const float* __restrict__ i2, const float* __restrict__ i3,
    const unsigned short* __restrict__ Amat,
    const float* __restrict__ beff,
    float* __restrict__ out)
{
    __shared__ __align__(16) short As[2 * BM * BK];
    __shared__ __align__(16) short Bs[BN * BK];

    int raw = blockIdx.x;
    int sb  = (raw & 7) * 256 + (raw >> 3);
    int ot = sb & 1;
    int xt = (sb >> 1) & 255;
    int b  = sb >> 9;
    int o0 = ot * BM, x0 = xt * BN;

    const unsigned short* Ab = Amat + ((size_t)b * NC + o0) * KTOT;

    int t = threadIdx.x;
    int wave = t >> 6, lane = t & 63;
    int wr = wave >> 1, wc = wave & 1;
    int lrow = lane & 15, lk = lane >> 4;

    f32x4 acc[4][4];
    #pragma unroll
    for (int mi = 0; mi < 4; ++mi)
        #pragma unroll
        for (int ni = 0; ni < 4; ++ni)
            acc[mi][ni] = (f32x4){0.f, 0.f, 0.f, 0.f};

    int xq = t & 31;
    int kb = (t >> 5) * 8;

    int ar = wave * 32 + (lane >> 3);
    int aq = (lane & 7) ^ (lane >> 3);
    const unsigned short* asrc = Ab + (size_t)ar * KTOT + aq * 8;

    float4 v[8];

    {
        #pragma unroll
        for (int p = 0; p < 4; ++p)
            __builtin_amdgcn_global_load_lds(
                (const __attribute__((address_space(1))) unsigned int*)
                    (asrc + (size_t)p * 8 * KTOT),
                (__attribute__((address_space(3))) unsigned int*)
                    (As + (wave * 32 + p * 8) * 64), 16, 0, 0);
        const float* Bb = i0 + (size_t)b * NC * DWH + x0;
        #pragma unroll
        for (int j = 0; j < 8; ++j)
            v[j] = *(const float4*)(Bb + (size_t)(kb + j) * DWH + xq * 4);
    }

    #pragma unroll 1
    for (int it = 0; it < KTOT / BK; ++it) {
        const short* Acur = As + (it & 1) * (BM * BK);
        short* Anx = As + ((it + 1) & 1) * (BM * BK);

        __builtin_amdgcn_s_barrier();
        __builtin_amdgcn_sched_barrier(0);

        {
            int ja = (it + 1 < 16) ? it + 1 : 15;
            #pragma unroll
            for (int p = 0; p < 4; ++p)
                __builtin_amdgcn_global_load_lds(
                    (const __attribute__((address_space(1))) unsigned int*)
                        (asrc + (size_t)p * 8 * KTOT + ja * BK),
                    (__attribute__((address_space(3))) unsigned int*)
                        (Anx + (wave * 32 + p * 8) * 64), 16, 0, 0);
        }
        __builtin_amdgcn_sched_barrier(0);

        uint4 pk[4];
        #pragma unroll
        for (int i = 0; i < 4; ++i) {
            unsigned w[4];
            #pragma unroll
            for (int j = 0; j < 4; ++j)
                w[j] = pack_bf16x2(((const float*)&v[2 * j])[i],
                                   ((const float*)&v[2 * j + 1])[i]);
            pk[i] = (uint4){w[0], w[1], w[2], w[3]};
        }

        {
            int itn = (it < 15) ? it + 1 : 15;
            int m = itn >> 2, cbase = (itn & 3) * 64;
            const float* Bb = (m == 0 ? i0 : m == 1 ? i1 : m == 2 ? i2 : i3)
                              + ((size_t)b * NC + cbase) * DWH + x0;
            #pragma unroll
            for (int j = 0; j < 8; ++j)
                v[j] = *(const float4*)(Bb + (size_t)(kb + j) * DWH + xq * 4);
        }
        __builtin_amdgcn_sched_barrier(0);

        #pragma unroll
        for (int i = 0; i < 4; ++i)
            *(uint4*)(&Bs[swzB(xq * 4 + i, t >> 5)]) = pk[i];

        asm volatile("s_waitcnt vmcnt(12) lgkmcnt(0)" ::: "memory");
        __builtin_amdgcn_s_barrier();
        __builtin_amdgcn_sched_barrier(0);

        #pragma unroll
        for (int kk = 0; kk < 2; ++kk) {
            int q = kk * 4 + lk;
            short8 af[4], bf[4];
            #pragma unroll
            for (int mi = 0; mi < 4; ++mi)
                af[mi] = *(const short8*)(&Acur[swzA(wr * 64 + mi * 16 + lrow, q)]);
            #pragma unroll
            for (int ni = 0; ni < 4; ++ni)
                bf[ni] = *(const short8*)(&Bs[swzB(wc * 64 + ni * 16 + lrow, q)]);
            __builtin_amdgcn_s_setprio(1);
            #pragma unroll
            for (int mi = 0; mi < 4; ++mi)
                #pragma unroll
                for (int ni = 0; ni < 4; ++ni)
                    acc[mi][ni] = __builtin_amdgcn_mfma_f32_16x16x32_bf16(
                        af[mi], bf[ni], acc[mi][ni], 0, 0, 0);
            __builtin_amdgcn_s_setprio(0);
        }
    }

    const float* beff_b = beff + b * NC + o0;
    float* outb = out + ((size_t)b * NC + o0) * DWH + x0;
    #pragma unroll
    for (int mi = 0; mi < 4; ++mi) {
        #pragma unroll
        for (int r4 = 0; r4 < 4; ++r4) {
            int row = wr * 64 + mi * 16 + lk * 4 + r4;
            float bias = beff_b[row];
            float* orow = outb + (size_t)row * DWH;
            #pragma unroll
            for (int ni = 0; ni < 4; ++ni) {
                int col = wc * 64 + ni * 16 + lrow;
                orow[col] = acc[mi][ni][r4] + bias;
            }
        }
    }
}

// ---------------------------------------------------------------------------
extern "C" void kernel_launch(void* const* d_in, const int* in_sizes, int n_in,
                              void* d_out, int out_size, void* d_ws, size_t ws_size,
                              hipStream_t stream) {
    const float* m1 = (const float*)d_in[0];
    const float* m2 = (const float*)d_in[1];
    const float* m3 = (const float*)d_in[2];
    const float* m4 = (const float*)d_in[3];
    const float* Wq = (const float*)d_in[4];
    const float* bq = (const float*)d_in[5];
    const float* Wk = (const float*)d_in[6];
    const float* bk = (const float*)d_in[7];
    const float* Wc = (const float*)d_in[8];
    const float* bcv = (const float*)d_in[9];
    float* out = (float*)d_out;

    const size_t BT_BYTES = (size_t)NB * KTOT * DWH * 2;   // 256 MB
    const size_t NEED = BT_BYTES + 524288 + 2097152 + 4096;

    if (ws_size >= NEED) {
        // NEW PATH: transcode+pool -> attn -> all-bf16 gemm
        unsigned short* Btr   = (unsigned short*)d_ws;
        float* pooled         = (float*)((char*)d_ws + BT_BYTES);
        unsigned short* Amat  = (unsigned short*)((char*)d_ws + BT_BYTES + 524288);
        float* beff           = (float*)((char*)d_ws + BT_BYTES + 524288 + 2097152);

        transpool_kernel<<<2048, 256, 0, stream>>>(m1, m2, m3, m4, Btr, pooled);
        attn_kernel<<<NB * NC, 64, 0, stream>>>(pooled, Wq, bq, Wk, bk, Wc, bcv,
                                                Amat, beff);
        gemm2_kernel<<<2048, 256, 0, stream>>>(Amat, Btr, beff, out);
    } else {
        // FALLBACK: measured R12 path
        float* pooled        = (float*)d_ws;
        unsigned short* Amat = (unsigned short*)((char*)d_ws + 524288);
        float* beff          = (float*)((char*)d_ws + 524288 + 2097152);

        pool_kernel<<<NB * NC * 4, 256, 0, stream>>>(m1, m2, m3, m4, pooled);
        attn_kernel<<<NB * NC, 64, 0, stream>>>(pooled, Wq, bq, Wk, bk, Wc, bcv,
                                                Amat, beff);
        gemm_kernel<<<(NB) * (NC / BM) * (DWH / BN), 256, 0, stream>>>(
            m1, m2, m3, m4, Amat, beff, out);
    }
}

// Round 14
// 295.177 us; speedup vs baseline: 1.0362x; 1.0362x over previous
//
#include <hip/hip_runtime.h>
#include <hip/hip_bf16.h>

// Problem constants
#define NB 4
#define NC 256
#define ND 32
#define WH 1024          // W*H
#define DWH 32768        // D*W*H
#define KTOT 1024        // 4 modalities * 256 channels

typedef __attribute__((ext_vector_type(8))) short short8;
typedef __attribute__((ext_vector_type(4))) float f32x4;

static __device__ __forceinline__ unsigned short f32_to_bf16(float f) {
    unsigned u = __builtin_bit_cast(unsigned, f);
    u = u + 0x7fff + ((u >> 16) & 1);   // round-to-nearest-even
    return (unsigned short)(u >> 16);
}

// HW-packed convert: v_cvt_pk_bf16_f32 (1 instr per pair).
static __device__ __forceinline__ unsigned pack_bf16x2(float lo, float hi) {
    __hip_bfloat162 h = __float22bfloat162_rn(make_float2(lo, hi));
    unsigned u;
    __builtin_memcpy(&u, &h, 4);
    return u;
}

// ===========================================================================
// K1: fused pool + bf16 transcode into GEMM-tile layout.
// Grid (b,m,cb,d) = 2048 blocks. Each block: 64 channels x 1024 x (one d).
// Bt layout: tiles [b][xt(256)][kt(16)] of [xl(128)][k(64)] bf16 (linear,
// 16KB each) -> gemm2 stages via global_load_lds with pre-swizzled source.
// R14 fixes vs R13: (1) stores remapped so each wave store-instr covers a
// CONTIGUOUS 1KB tile span (was 16B-per-64B scatter over 4KB); (2) LDS
// pitch 133 + scalar writes: write banks 5a+4b (conflict-free), transpose-
// read banks 8(sl%4)+(l>>3) (2-way = free).
// ===========================================================================
__global__ __launch_bounds__(256) void transpool_kernel(
    const float* __restrict__ i0, const float* __restrict__ i1,
    const float* __restrict__ i2, const float* __restrict__ i3,
    unsigned short* __restrict__ Bt, float* __restrict__ pooled)
{
    __shared__ float lds[64 * 133];   // 34,048 B, pitch 133 floats
    int bid = blockIdx.x;
    int d  = bid & 31;
    int cb = (bid >> 5) & 3;
    int m  = (bid >> 7) & 3;
    int b  = bid >> 9;
    const float* base = (m == 0 ? i0 : m == 1 ? i1 : m == 2 ? i2 : i3)
                        + ((size_t)(b * NC + cb * 64)) * DWH + d * WH;
    int t  = threadIdx.x;
    int rl = t >> 3;                 // 0..31: covers c=rl and c=32+rl
    int xo = t & 7;                  // 16B slot within the 128-float chunk
    int sl = t & 7;                  // store phase: k-slot (8 c's)

    float pc0 = 0.f, pc1 = 0.f;
    float4 v0[4], v1[4];

    // ---- prologue: load chunk 0, accumulate, stage to LDS (scalar) ----
    #pragma unroll
    for (int j = 0; j < 4; ++j) {
        v0[j] = *(const float4*)(base + (size_t)rl * DWH + (xo + 8 * j) * 4);
        v1[j] = *(const float4*)(base + (size_t)(32 + rl) * DWH + (xo + 8 * j) * 4);
    }
    #pragma unroll
    for (int j = 0; j < 4; ++j) {
        pc0 += v0[j].x + v0[j].y + v0[j].z + v0[j].w;
        pc1 += v1[j].x + v1[j].y + v1[j].z + v1[j].w;
        int xb = (xo + 8 * j) * 4;
        lds[rl * 133 + xb + 0] = v0[j].x;  lds[rl * 133 + xb + 1] = v0[j].y;
        lds[rl * 133 + xb + 2] = v0[j].z;  lds[rl * 133 + xb + 3] = v0[j].w;
        lds[(32 + rl) * 133 + xb + 0] = v1[j].x;  lds[(32 + rl) * 133 + xb + 1] = v1[j].y;
        lds[(32 + rl) * 133 + xb + 2] = v1[j].z;  lds[(32 + rl) * 133 + xb + 3] = v1[j].w;
    }
    __syncthreads();

    // tile base: chunk s -> tile (xt = d*8+s, kt = m*4+cb)
    unsigned short* tb0 = Bt + (((size_t)b * 256 + d * 8) * 16 + (m * 4 + cb)) * 8192;

    #pragma unroll 1
    for (int s = 0; s < 8; ++s) {
        if (s < 7) {   // prefetch chunk s+1 (consumed after next barrier)
            const float* bs = base + (s + 1) * 128;
            #pragma unroll
            for (int j = 0; j < 4; ++j) {
                v0[j] = *(const float4*)(bs + (size_t)rl * DWH + (xo + 8 * j) * 4);
                v1[j] = *(const float4*)(bs + (size_t)(32 + rl) * DWH + (xo + 8 * j) * 4);
            }
        }
        // ---- transpose-read + pack + coalesced store ----
        {
            unsigned short* tile = tb0 + (size_t)s * 16 * 8192;
            #pragma unroll
            for (int u = 0; u < 4; ++u) {
                int row = u * 32 + rl;           // x-row 0..127
                unsigned w0 = pack_bf16x2(lds[(8 * sl + 0) * 133 + row],
                                          lds[(8 * sl + 1) * 133 + row]);
                unsigned w1 = pack_bf16x2(lds[(8 * sl + 2) * 133 + row],
                                          lds[(8 * sl + 3) * 133 + row]);
                unsigned w2 = pack_bf16x2(lds[(8 * sl + 4) * 133 + row],
                                          lds[(8 * sl + 5) * 133 + row]);
                unsigned w3 = pack_bf16x2(lds[(8 * sl + 6) * 133 + row],
                                          lds[(8 * sl + 7) * 133 + row]);
                *(uint4*)(tile + (size_t)row * 64 + sl * 8) =
                    (uint4){w0, w1, w2, w3};
            }
        }
        __syncthreads();
        if (s < 7) {   // accumulate + stage chunk s+1
            #pragma unroll
            for (int j = 0; j < 4; ++j) {
                pc0 += v0[j].x + v0[j].y + v0[j].z + v0[j].w;
                pc1 += v1[j].x + v1[j].y + v1[j].z + v1[j].w;
                int xb = (xo + 8 * j) * 4;
                lds[rl * 133 + xb + 0] = v0[j].x;  lds[rl * 133 + xb + 1] = v0[j].y;
                lds[rl * 133 + xb + 2] = v0[j].z;  lds[rl * 133 + xb + 3] = v0[j].w;
                lds[(32 + rl) * 133 + xb + 0] = v1[j].x;  lds[(32 + rl) * 133 + xb + 1] = v1[j].y;
                lds[(32 + rl) * 133 + xb + 2] = v1[j].z;  lds[(32 + rl) * 133 + xb + 3] = v1[j].w;
            }
            __syncthreads();
        }
    }

    // ---- pool reduce over the 8 xo-lanes ----
    pc0 += __shfl_down(pc0, 4, 64); pc1 += __shfl_down(pc1, 4, 64);
    pc0 += __shfl_down(pc0, 2, 64); pc1 += __shfl_down(pc1, 2, 64);
    pc0 += __shfl_down(pc0, 1, 64); pc1 += __shfl_down(pc1, 1, 64);
    if (xo == 0) {
        pooled[((size_t)b * NC + cb * 64 + rl) * 128 + m * 32 + d]      = pc0 * (1.0f / 1024.0f);
        pooled[((size_t)b * NC + cb * 64 + 32 + rl) * 128 + m * 32 + d] = pc1 * (1.0f / 1024.0f);
    }
}

// ===========================================================================
// FALLBACK K1: pool only (used when ws too small).
// ===========================================================================
__global__ __launch_bounds__(256) void pool_kernel(
    const float* __restrict__ i0, const float* __restrict__ i1,
    const float* __restrict__ i2, const float* __restrict__ i3,
    float* __restrict__ pooled)
{
    int bid = blockIdx.x;
    int m   = bid & 3;
    int bc  = bid >> 2;
    const float* src = (m == 0 ? i0 : m == 1 ? i1 : m == 2 ? i2 : i3)
                       + (size_t)bc * DWH;
    int t = threadIdx.x;
    int d   = t >> 3;
    int sub = t & 7;

    const float4* row = (const float4*)(src + (size_t)d * WH);
    float4 a0 = {0.f, 0.f, 0.f, 0.f}, a1 = {0.f, 0.f, 0.f, 0.f};
    #pragma unroll
    for (int j = 0; j < 16; ++j) {
        float4 u = row[sub + 8 * (2 * j)];
        float4 w = row[sub + 8 * (2 * j + 1)];
        a0.x += u.x; a0.y += u.y; a0.z += u.z; a0.w += u.w;
        a1.x += w.x; a1.y += w.y; a1.z += w.z; a1.w += w.w;
    }
    float s = (a0.x + a0.y) + (a0.z + a0.w) + (a1.x + a1.y) + (a1.z + a1.w);
    s += __shfl_down(s, 4, 64);
    s += __shfl_down(s, 2, 64);
    s += __shfl_down(s, 1, 64);
    if (sub == 0) pooled[bc * 128 + m * 32 + d] = s * (1.0f / 1024.0f);
}

// ---------------------------------------------------------------------------
// Kernel 2: attention weights + effective GEMM A-matrix + effective bias.
// ---------------------------------------------------------------------------
__global__ __launch_bounds__(64) void attn_kernel(
    const float* __restrict__ pooled,
    const float* __restrict__ Wq, const float* __restrict__ bq,
    const float* __restrict__ Wk, const float* __restrict__ bk,
    const float* __restrict__ Wc, const float* __restrict__ bcv,
    unsigned short* __restrict__ Amat, float* __restrict__ beff)
{
    int bc_idx = blockIdx.x;             // b*NC + c
    int lane = threadIdx.x;
    int e = lane & 31;
    const float* P = pooled + bc_idx * 128;

    float q = 0.f, kv[4] = {0.f, 0.f, 0.f, 0.f};
    for (int d = 0; d < 32; ++d) {
        float pq = P[d];
        float wq = Wq[e * 32 + d], wk = Wk[e * 32 + d];
        q += pq * wq;
        #pragma unroll
        for (int m = 0; m < 4; ++m) kv[m] += P[m * 32 + d] * wk;
    }
    q += bq[e];
    #pragma unroll
    for (int m = 0; m < 4; ++m) kv[m] += bk[e];

    float lg[4];
    #pragma unroll
    for (int m = 0; m < 4; ++m) {
        float p = q * kv[m];
        #pragma unroll
        for (int off = 16; off; off >>= 1) p += __shfl_xor(p, off, 32);
        lg[m] = p * 0.17677669529663687f;    // 1/sqrt(32)
    }
    float mx = fmaxf(fmaxf(lg[0], lg[1]), fmaxf(lg[2], lg[3]));
    float ex[4], s = 0.f;
    #pragma unroll
    for (int m = 0; m < 4; ++m) { ex[m] = __expf(lg[m] - mx); s += ex[m]; }
    float a[4];
    #pragma unroll
    for (int m = 0; m < 4; ++m) a[m] = ex[m] / s;

    int c = bc_idx & 255;
    if (lane == 0) {
        float be = 0.f;
        #pragma unroll
        for (int m = 0; m < 4; ++m) be += a[m] * bcv[m * NC + c];
        beff[bc_idx] = be;
    }
    unsigned short* Arow = Amat + (size_t)bc_idx * KTOT;
    #pragma unroll
    for (int j = 0; j < 16; ++j) {
        int k = j * 64 + lane;
        int m = k >> 8, cin = k & 255;
        float v = a[m] * Wc[(m * NC + c) * NC + cin];
        Arow[k] = f32_to_bf16(v);
    }
}

#define BM 128
#define BN 128
#define BK 64

static __device__ __forceinline__ int swzA(int row, int chunk) {
    // ushort units: row stride 64 ushorts (=128B), chunk = 8 ushorts (=16B)
    return row * 64 + ((chunk ^ (row & 7)) << 3);
}
static __device__ __forceinline__ int swzB(int row, int chunk) {
    return row * 64 + ((chunk ^ ((row >> 1) & 7)) << 3);
}

// ===========================================================================
// K3: all-bf16 GEMM (verified R13, ~100 us). A and B both staged via
// global_load_lds (pre-swizzled source, linear LDS dest), double-buffered
// one K-tile ahead; the only in-loop wait is counted vmcnt(8).
// ===========================================================================
__global__ __launch_bounds__(256, 2) void gemm2_kernel(
    const unsigned short* __restrict__ Amat,
    const unsigned short* __restrict__ Bt,
    const float* __restrict__ beff,
    float* __restrict__ out)
{
    __shared__ __align__(16) short As[2 * BM * BK];   // 32KB dbuf
    __shared__ __align__(16) short Bs[2 * BN * BK];   // 32KB dbuf

    int raw = blockIdx.x;
    int sb  = (raw & 7) * 256 + (raw >> 3);
    int ot = sb & 1;
    int xt = (sb >> 1) & 255;
    int b  = sb >> 9;
    int o0 = ot * BM, x0 = xt * BN;

    int t = threadIdx.x;
    int wave = t >> 6, lane = t & 63;
    int wr = wave >> 1, wc = wave & 1;
    int lrow = lane & 15, lk = lane >> 4;
    int lr8 = lane >> 3;
    int aq  = (lane & 7) ^ lr8;

    const unsigned short* asrc = Amat + ((size_t)b * NC + o0) * KTOT
                                 + (size_t)(wave * 32 + lr8) * KTOT + aq * 8;
    const unsigned short* bsrc = Bt + ((size_t)b * 256 + xt) * 16 * 8192
                                 + (size_t)(wave * 32 + lr8) * 64 + aq * 8;

    f32x4 acc[4][4];
    #pragma unroll
    for (int mi = 0; mi < 4; ++mi)
        #pragma unroll
        for (int ni = 0; ni < 4; ++ni)
            acc[mi][ni] = (f32x4){0.f, 0.f, 0.f, 0.f};

    // ---- prologue: issue tile 0 into buf0 (8 vmem per wave) ----
    #pragma unroll
    for (int p = 0; p < 4; ++p)
        __builtin_amdgcn_global_load_lds(
            (const __attribute__((address_space(1))) unsigned int*)
                (asrc + (size_t)p * 8 * KTOT),
            (__attribute__((address_space(3))) unsigned int*)
                (As + (wave * 32 + p * 8) * 64), 16, 0, 0);
    #pragma unroll
    for (int p = 0; p < 4; ++p)
        __builtin_amdgcn_global_load_lds(
            (const __attribute__((address_space(1))) unsigned int*)
                (bsrc + (size_t)p * 8 * 64),
            (__attribute__((address_space(3))) unsigned int*)
                (Bs + (wave * 32 + p * 8) * 64), 16, 0, 0);
    __builtin_amdgcn_sched_barrier(0);

    #pragma unroll 1
    for (int it = 0; it < 16; ++it) {
        // ---- issue next tile -> buf^1 (8 vmem; last iter re-issues 15) ----
        int ja = (it < 15) ? it + 1 : 15;
        int bo = ((it + 1) & 1) * (BM * BK);
        #pragma unroll
        for (int p = 0; p < 4; ++p)
            __builtin_amdgcn_global_load_lds(
                (const __attribute__((address_space(1))) unsigned int*)
                    (asrc + (size_t)p * 8 * KTOT + ja * BK),
                (__attribute__((address_space(3))) unsigned int*)
                    (As + bo + (wave * 32 + p * 8) * 64), 16, 0, 0);
        #pragma unroll
        for (int p = 0; p < 4; ++p)
            __builtin_amdgcn_global_load_lds(
                (const __attribute__((address_space(1))) unsigned int*)
                    (bsrc + (size_t)ja * 8192 + p * 8 * 64),
                (__attribute__((address_space(3))) unsigned int*)
                    (Bs + bo + (wave * 32 + p * 8) * 64), 16, 0, 0);
        __builtin_amdgcn_sched_barrier(0);

        // ---- current tile's 8 loads landed (8 newer in flight) ----
        asm volatile("s_waitcnt vmcnt(8)" ::: "memory");
        __builtin_amdgcn_s_barrier();
        __builtin_amdgcn_sched_barrier(0);

        // ---- compute on buf cur ----
        const short* Acur = As + (it & 1) * (BM * BK);
        const short* Bcur = Bs + (it & 1) * (BM * BK);
        #pragma unroll
        for (int kk = 0; kk < 2; ++kk) {
            int q = kk * 4 + lk;
            short8 af[4], bf[4];
            #pragma unroll
            for (int mi = 0; mi < 4; ++mi)
                af[mi] = *(const short8*)(&Acur[swzA(wr * 64 + mi * 16 + lrow, q)]);
            #pragma unroll
            for (int ni = 0; ni < 4; ++ni)
                bf[ni] = *(const short8*)(&Bcur[swzA(wc * 64 + ni * 16 + lrow, q)]);
            __builtin_amdgcn_s_setprio(1);
            #pragma unroll
            for (int mi = 0; mi < 4; ++mi)
                #pragma unroll
                for (int ni = 0; ni < 4; ++ni)
                    acc[mi][ni] = __builtin_amdgcn_mfma_f32_16x16x32_bf16(
                        af[mi], bf[ni], acc[mi][ni], 0, 0, 0);
            __builtin_amdgcn_s_setprio(0);
        }
        // ---- all waves done reading buf cur (next iter overwrites it) ----
        __builtin_amdgcn_s_barrier();
        __builtin_amdgcn_sched_barrier(0);
    }

    // ---- epilogue ----
    const float* beff_b = beff + b * NC + o0;
    float* outb = out + ((size_t)b * NC + o0) * DWH + x0;
    #pragma unroll
    for (int mi = 0; mi < 4; ++mi) {
        #pragma unroll
        for (int r4 = 0; r4 < 4; ++r4) {
            int row = wr * 64 + mi * 16 + lk * 4 + r4;
            float bias = beff_b[row];
            float* orow = outb + (size_t)row * DWH;
            #pragma unroll
            for (int ni = 0; ni < 4; ++ni) {
                int col = wc * 64 + ni * 16 + lrow;
                orow[col] = acc[mi][ni][r4] + bias;
            }
        }
    }
}

// ===========================================================================
// FALLBACK K3: R12 gemm (fp32 B reg-staged + cvt_pk).
// ===========================================================================
__global__ __launch_bounds__(256, 3) void gemm_kernel(
    const float* __restrict__ i0, const float* __restrict__ i1,
    const float* __restrict__ i2, const float* __restrict__ i3,
    const unsigned short* __restrict__ Amat,
    const float* __restrict__ beff,
    float* __restrict__ out)
{
    __shared__ __align__(16) short As[2 * BM * BK];
    __shared__ __align__(16) short Bs[BN * BK];

    int raw = blockIdx.x;
    int sb  = (raw & 7) * 256 + (raw >> 3);
    int ot = sb & 1;
    int xt = (sb >> 1) & 255;
    int b  = sb >> 9;
    int o0 = ot * BM, x0 = xt * BN;

    const unsigned short* Ab = Amat + ((size_t)b * NC + o0) * KTOT;

    int t = threadIdx.x;
    int wave = t >> 6, lane = t & 63;
    int wr = wave >> 1, wc = wave & 1;
    int lrow = lane & 15, lk = lane >> 4;

    f32x4 acc[4][4];
    #pragma unroll
    for (int mi = 0; mi < 4; ++mi)
        #pragma unroll
        for (int ni = 0; ni < 4; ++ni)
            acc[mi][ni] = (f32x4){0.f, 0.f, 0.f, 0.f};

    int xq = t & 31;
    int kb = (t >> 5) * 8;

    int ar = wave * 32 + (lane >> 3);
    int aq = (lane & 7) ^ (lane >> 3);
    const unsigned short* asrc = Ab + (size_t)ar * KTOT + aq * 8;

    float4 v[8];

    {
        #pragma unroll
        for (int p = 0; p < 4; ++p)
            __builtin_amdgcn_global_load_lds(
                (const __attribute__((address_space(1))) unsigned int*)
                    (asrc + (size_t)p * 8 * KTOT),
                (__attribute__((address_space(3))) unsigned int*)
                    (As + (wave * 32 + p * 8) * 64), 16, 0, 0);
        const float* Bb = i0 + (size_t)b * NC * DWH + x0;
        #pragma unroll
        for (int j = 0; j < 8; ++j)
            v[j] = *(const float4*)(Bb + (size_t)(kb + j) * DWH + xq * 4);
    }

    #pragma unroll 1
    for (int it = 0; it < KTOT / BK; ++it) {
        const short* Acur = As + (it & 1) * (BM * BK);
        short* Anx = As + ((it + 1) & 1) * (BM * BK);

        __builtin_amdgcn_s_barrier();
        __builtin_amdgcn_sched_barrier(0);

        {
            int ja = (it + 1 < 16) ? it + 1 : 15;
            #pragma unroll
            for (int p = 0; p < 4; ++p)
                __builtin_amdgcn_global_load_lds(
                    (const __attribute__((address_space(1))) unsigned int*)
                        (asrc + (size_t)p * 8 * KTOT + ja * BK),
                    (__attribute__((address_space(3))) unsigned int*)
                        (Anx + (wave * 32 + p * 8) * 64), 16, 0, 0);
        }
        __builtin_amdgcn_sched_barrier(0);

        uint4 pk[4];
        #pragma unroll
        for (int i = 0; i < 4; ++i) {
            unsigned w[4];
            #pragma unroll
            for (int j = 0; j < 4; ++j)
                w[j] = pack_bf16x2(((const float*)&v[2 * j])[i],
                                   ((const float*)&v[2 * j + 1])[i]);
            pk[i] = (uint4){w[0], w[1], w[2], w[3]};
        }

        {
            int itn = (it < 15) ? it + 1 : 15;
            int m = itn >> 2, cbase = (itn & 3) * 64;
            const float* Bb = (m == 0 ? i0 : m == 1 ? i1 : m == 2 ? i2 : i3)
                              + ((size_t)b * NC + cbase) * DWH + x0;
            #pragma unroll
            for (int j = 0; j < 8; ++j)
                v[j] = *(const float4*)(Bb + (size_t)(kb + j) * DWH + xq * 4);
        }
        __builtin_amdgcn_sched_barrier(0);

        #pragma unroll
        for (int i = 0; i < 4; ++i)
            *(uint4*)(&Bs[swzB(xq * 4 + i, t >> 5)]) = pk[i];

        asm volatile("s_waitcnt vmcnt(12) lgkmcnt(0)" ::: "memory");
        __builtin_amdgcn_s_barrier();
        __builtin_amdgcn_sched_barrier(0);

        #pragma unroll
        for (int kk = 0; kk < 2; ++kk) {
            int q = kk * 4 + lk;
            short8 af[4], bf[4];
            #pragma unroll
            for (int mi = 0; mi < 4; ++mi)
                af[mi] = *(const short8*)(&Acur[swzA(wr * 64 + mi * 16 + lrow, q)]);
            #pragma unroll
            for (int ni = 0; ni < 4; ++ni)
                bf[ni] = *(const short8*)(&Bs[swzB(wc * 64 + ni * 16 + lrow, q)]);
            __builtin_amdgcn_s_setprio(1);
            #pragma unroll
            for (int mi = 0; mi < 4; ++mi)
                #pragma unroll
                for (int ni = 0; ni < 4; ++ni)
                    acc[mi][ni] = __builtin_amdgcn_mfma_f32_16x16x32_bf16(
                        af[mi], bf[ni], acc[mi][ni], 0, 0, 0);
            __builtin_amdgcn_s_setprio(0);
        }
    }

    const float* beff_b = beff + b * NC + o0;
    float* outb = out + ((size_t)b * NC + o0) * DWH + x0;
    #pragma unroll
    for (int mi = 0; mi < 4; ++mi) {
        #pragma unroll
        for (int r4 = 0; r4 < 4; ++r4) {
            int row = wr * 64 + mi * 16 + lk * 4 + r4;
            float bias = beff_b[row];
            float* orow = outb + (size_t)row * DWH;
            #pragma unroll
            for (int ni = 0; ni < 4; ++ni) {
                int col = wc * 64 + ni * 16 + lrow;
                orow[col] = acc[mi][ni][r4] + bias;
            }
        }
    }
}

// ---------------------------------------------------------------------------
extern "C" void kernel_launch(void* const* d_in, const int* in_sizes, int n_in,
                              void* d_out, int out_size, void* d_ws, size_t ws_size,
                              hipStream_t stream) {
    const float* m1 = (const float*)d_in[0];
    const float* m2 = (const float*)d_in[1];
    const float* m3 = (const float*)d_in[2];
    const float* m4 = (const float*)d_in[3];
    const float* Wq = (const float*)d_in[4];
    const float* bq = (const float*)d_in[5];
    const float* Wk = (const float*)d_in[6];
    const float* bk = (const float*)d_in[7];
    const float* Wc = (const float*)d_in[8];
    const float* bcv = (const float*)d_in[9];
    float* out = (float*)d_out;

    const size_t BT_BYTES = (size_t)NB * KTOT * DWH * 2;   // 256 MB
    const size_t NEED = BT_BYTES + 524288 + 2097152 + 4096;

    if (ws_size >= NEED) {
        // transcode+pool -> attn -> all-bf16 gemm
        unsigned short* Btr   = (unsigned short*)d_ws;
        float* pooled         = (float*)((char*)d_ws + BT_BYTES);
        unsigned short* Amat  = (unsigned short*)((char*)d_ws + BT_BYTES + 524288);
        float* beff           = (float*)((char*)d_ws + BT_BYTES + 524288 + 2097152);

        transpool_kernel<<<2048, 256, 0, stream>>>(m1, m2, m3, m4, Btr, pooled);
        attn_kernel<<<NB * NC, 64, 0, stream>>>(pooled, Wq, bq, Wk, bk, Wc, bcv,
                                                Amat, beff);
        gemm2_kernel<<<2048, 256, 0, stream>>>(Amat, Btr, beff, out);
    } else {
        // FALLBACK: measured R12 path
        float* pooled        = (float*)d_ws;
        unsigned short* Amat = (unsigned short*)((char*)d_ws + 524288);
        float* beff          = (float*)((char*)d_ws + 524288 + 2097152);

        pool_kernel<<<NB * NC * 4, 256, 0, stream>>>(m1, m2, m3, m4, pooled);
        attn_kernel<<<NB * NC, 64, 0, stream>>>(pooled, Wq, bq, Wk, bk, Wc, bcv,
                                                Amat, beff);
        gemm_kernel<<<(NB) * (NC / BM) * (DWH / BN), 256, 0, stream>>>(
            m1, m2, m3, m4, Amat, beff, out);
    }
}

// Round 15
// 289.738 us; speedup vs baseline: 1.0557x; 1.0188x over previous
//
#include <hip/hip_runtime.h>
#include <hip/hip_bf16.h>

// Problem constants
#define NB 4
#define NC 256
#define ND 32
#define WH 1024          // W*H
#define DWH 32768        // D*W*H
#define KTOT 1024        // 4 modalities * 256 channels

typedef __attribute__((ext_vector_type(8))) short short8;
typedef __attribute__((ext_vector_type(4))) float f32x4;

static __device__ __forceinline__ unsigned short f32_to_bf16(float f) {
    unsigned u = __builtin_bit_cast(unsigned, f);
    u = u + 0x7fff + ((u >> 16) & 1);   // round-to-nearest-even
    return (unsigned short)(u >> 16);
}

// HW-packed convert: v_cvt_pk_bf16_f32 (1 instr per pair).
static __device__ __forceinline__ unsigned pack_bf16x2(float lo, float hi) {
    __hip_bfloat162 h = __float22bfloat162_rn(make_float2(lo, hi));
    unsigned u;
    __builtin_memcpy(&u, &h, 4);
    return u;
}

// ===========================================================================
// K1: fused pool + bf16 transcode into GEMM-tile layout.
// R15 change vs R14: DEPTH-2 register prefetch (va/vb, manual 2-unroll) --
// loads for chunk s+2 issued at iter s, consumed ~1.5 chunk-phases later,
// covering the ~900cy HBM latency that was exposed at every chunk barrier.
// LDS scheme (pitch 133, scalar both sides: 2-way = free) and the coalesced
// 1KB-span stores are IDENTICAL to R14 (proven correct).
// ===========================================================================
#define TP_LOAD(V, S)                                                         \
  { const float* bs_ = base + (S) * 128;                                      \
    _Pragma("unroll")                                                         \
    for (int j_ = 0; j_ < 4; ++j_) {                                          \
      V[j_]     = *(const float4*)(bs_ + (size_t)rl * DWH + (xo + 8 * j_) * 4);\
      V[j_ + 4] = *(const float4*)(bs_ + (size_t)(32 + rl) * DWH + (xo + 8 * j_) * 4);\
    } }

#define TP_STAGE(V)                                                           \
  { _Pragma("unroll")                                                         \
    for (int j_ = 0; j_ < 4; ++j_) {                                          \
      float4 u_ = V[j_], w_ = V[j_ + 4];                                      \
      pc0 += u_.x + u_.y + u_.z + u_.w;                                       \
      pc1 += w_.x + w_.y + w_.z + w_.w;                                       \
      int xb_ = (xo + 8 * j_) * 4;                                            \
      lds[rl * 133 + xb_ + 0] = u_.x;  lds[rl * 133 + xb_ + 1] = u_.y;        \
      lds[rl * 133 + xb_ + 2] = u_.z;  lds[rl * 133 + xb_ + 3] = u_.w;        \
      lds[(32 + rl) * 133 + xb_ + 0] = w_.x;  lds[(32 + rl) * 133 + xb_ + 1] = w_.y;\
      lds[(32 + rl) * 133 + xb_ + 2] = w_.z;  lds[(32 + rl) * 133 + xb_ + 3] = w_.w;\
    } }

#define TP_STORE(S)                                                           \
  { unsigned short* tile_ = tb0 + (size_t)(S) * 16 * 8192;                    \
    _Pragma("unroll")                                                         \
    for (int u_ = 0; u_ < 4; ++u_) {                                          \
      int row_ = u_ * 32 + rl;                                                \
      unsigned w0_ = pack_bf16x2(lds[(8 * xo + 0) * 133 + row_],              \
                                 lds[(8 * xo + 1) * 133 + row_]);             \
      unsigned w1_ = pack_bf16x2(lds[(8 * xo + 2) * 133 + row_],              \
                                 lds[(8 * xo + 3) * 133 + row_]);             \
      unsigned w2_ = pack_bf16x2(lds[(8 * xo + 4) * 133 + row_],              \
                                 lds[(8 * xo + 5) * 133 + row_]);             \
      unsigned w3_ = pack_bf16x2(lds[(8 * xo + 6) * 133 + row_],              \
                                 lds[(8 * xo + 7) * 133 + row_]);             \
      *(uint4*)(tile_ + (size_t)row_ * 64 + xo * 8) = (uint4){w0_, w1_, w2_, w3_};\
    } }

__global__ __launch_bounds__(256) void transpool_kernel(
    const float* __restrict__ i0, const float* __restrict__ i1,
    const float* __restrict__ i2, const float* __restrict__ i3,
    unsigned short* __restrict__ Bt, float* __restrict__ pooled)
{
    __shared__ float lds[64 * 133];   // 34,048 B, pitch 133 floats
    int bid = blockIdx.x;
    int d  = bid & 31;
    int cb = (bid >> 5) & 3;
    int m  = (bid >> 7) & 3;
    int b  = bid >> 9;
    const float* base = (m == 0 ? i0 : m == 1 ? i1 : m == 2 ? i2 : i3)
                        + ((size_t)(b * NC + cb * 64)) * DWH + d * WH;
    int t  = threadIdx.x;
    int rl = t >> 3;                 // 0..31: covers c=rl and c=32+rl
    int xo = t & 7;                  // 16B slot / store k-slot

    float pc0 = 0.f, pc1 = 0.f;
    float4 va[8], vb[8];

    // tile base: chunk s -> tile (xt = d*8+s, kt = m*4+cb)
    unsigned short* tb0 = Bt + (((size_t)b * 256 + d * 8) * 16 + (m * 4 + cb)) * 8192;

    // ---- prologue: chunks 0,1 in flight; stage chunk 0 ----
    TP_LOAD(va, 0);
    TP_LOAD(vb, 1);
    TP_STAGE(va);              // waits on va's 8 loads only
    __syncthreads();

    #pragma unroll 1
    for (int s2 = 0; s2 < 4; ++s2) {
        int s = 2 * s2;
        if (s2 < 3) TP_LOAD(va, s + 2);   // issue chunk s+2 (consumed 1.5 phases later)
        TP_STORE(s);
        __syncthreads();
        TP_STAGE(vb);                     // chunk s+1 (loaded 2 phases ago)
        __syncthreads();
        if (s2 < 3) TP_LOAD(vb, s + 3);   // issue chunk s+3
        TP_STORE(s + 1);
        __syncthreads();
        if (s2 < 3) {
            TP_STAGE(va);                 // chunk s+2
            __syncthreads();
        }
    }

    // ---- pool reduce over the 8 xo-lanes ----
    pc0 += __shfl_down(pc0, 4, 64); pc1 += __shfl_down(pc1, 4, 64);
    pc0 += __shfl_down(pc0, 2, 64); pc1 += __shfl_down(pc1, 2, 64);
    pc0 += __shfl_down(pc0, 1, 64); pc1 += __shfl_down(pc1, 1, 64);
    if (xo == 0) {
        pooled[((size_t)b * NC + cb * 64 + rl) * 128 + m * 32 + d]      = pc0 * (1.0f / 1024.0f);
        pooled[((size_t)b * NC + cb * 64 + 32 + rl) * 128 + m * 32 + d] = pc1 * (1.0f / 1024.0f);
    }
}

// ===========================================================================
// FALLBACK K1: pool only (used when ws too small).
// ===========================================================================
__global__ __launch_bounds__(256) void pool_kernel(
    const float* __restrict__ i0, const float* __restrict__ i1,
    const float* __restrict__ i2, const float* __restrict__ i3,
    float* __restrict__ pooled)
{
    int bid = blockIdx.x;
    int m   = bid & 3;
    int bc  = bid >> 2;
    const float* src = (m == 0 ? i0 : m == 1 ? i1 : m == 2 ? i2 : i3)
                       + (size_t)bc * DWH;
    int t = threadIdx.x;
    int d   = t >> 3;
    int sub = t & 7;

    const float4* row = (const float4*)(src + (size_t)d * WH);
    float4 a0 = {0.f, 0.f, 0.f, 0.f}, a1 = {0.f, 0.f, 0.f, 0.f};
    #pragma unroll
    for (int j = 0; j < 16; ++j) {
        float4 u = row[sub + 8 * (2 * j)];
        float4 w = row[sub + 8 * (2 * j + 1)];
        a0.x += u.x; a0.y += u.y; a0.z += u.z; a0.w += u.w;
        a1.x += w.x; a1.y += w.y; a1.z += w.z; a1.w += w.w;
    }
    float s = (a0.x + a0.y) + (a0.z + a0.w) + (a1.x + a1.y) + (a1.z + a1.w);
    s += __shfl_down(s, 4, 64);
    s += __shfl_down(s, 2, 64);
    s += __shfl_down(s, 1, 64);
    if (sub == 0) pooled[bc * 128 + m * 32 + d] = s * (1.0f / 1024.0f);
}

// ---------------------------------------------------------------------------
// Kernel 2: attention weights + effective GEMM A-matrix + effective bias.
// ---------------------------------------------------------------------------
__global__ __launch_bounds__(64) void attn_kernel(
    const float* __restrict__ pooled,
    const float* __restrict__ Wq, const float* __restrict__ bq,
    const float* __restrict__ Wk, const float* __restrict__ bk,
    const float* __restrict__ Wc, const float* __restrict__ bcv,
    unsigned short* __restrict__ Amat, float* __restrict__ beff)
{
    int bc_idx = blockIdx.x;             // b*NC + c
    int lane = threadIdx.x;
    int e = lane & 31;
    const float* P = pooled + bc_idx * 128;

    float q = 0.f, kv[4] = {0.f, 0.f, 0.f, 0.f};
    for (int d = 0; d < 32; ++d) {
        float pq = P[d];
        float wq = Wq[e * 32 + d], wk = Wk[e * 32 + d];
        q += pq * wq;
        #pragma unroll
        for (int m = 0; m < 4; ++m) kv[m] += P[m * 32 + d] * wk;
    }
    q += bq[e];
    #pragma unroll
    for (int m = 0; m < 4; ++m) kv[m] += bk[e];

    float lg[4];
    #pragma unroll
    for (int m = 0; m < 4; ++m) {
        float p = q * kv[m];
        #pragma unroll
        for (int off = 16; off; off >>= 1) p += __shfl_xor(p, off, 32);
        lg[m] = p * 0.17677669529663687f;    // 1/sqrt(32)
    }
    float mx = fmaxf(fmaxf(lg[0], lg[1]), fmaxf(lg[2], lg[3]));
    float ex[4], s = 0.f;
    #pragma unroll
    for (int m = 0; m < 4; ++m) { ex[m] = __expf(lg[m] - mx); s += ex[m]; }
    float a[4];
    #pragma unroll
    for (int m = 0; m < 4; ++m) a[m] = ex[m] / s;

    int c = bc_idx & 255;
    if (lane == 0) {
        float be = 0.f;
        #pragma unroll
        for (int m = 0; m < 4; ++m) be += a[m] * bcv[m * NC + c];
        beff[bc_idx] = be;
    }
    unsigned short* Arow = Amat + (size_t)bc_idx * KTOT;
    #pragma unroll
    for (int j = 0; j < 16; ++j) {
        int k = j * 64 + lane;
        int m = k >> 8, cin = k & 255;
        float v = a[m] * Wc[(m * NC + c) * NC + cin];
        Arow[k] = f32_to_bf16(v);
    }
}

#define BM 128
#define BN 128
#define BK 64

static __device__ __forceinline__ int swzA(int row, int chunk) {
    // ushort units: row stride 64 ushorts (=128B), chunk = 8 ushorts (=16B)
    return row * 64 + ((chunk ^ (row & 7)) << 3);
}
static __device__ __forceinline__ int swzB(int row, int chunk) {
    return row * 64 + ((chunk ^ ((row >> 1) & 7)) << 3);
}

// ===========================================================================
// K3: all-bf16 GEMM (verified R13/R14, ~100 us). A and B both staged via
// global_load_lds (pre-swizzled source, linear LDS dest), double-buffered
// one K-tile ahead; the only in-loop wait is counted vmcnt(8).
// ===========================================================================
__global__ __launch_bounds__(256, 2) void gemm2_kernel(
    const unsigned short* __restrict__ Amat,
    const unsigned short* __restrict__ Bt,
    const float* __restrict__ beff,
    float* __restrict__ out)
{
    __shared__ __align__(16) short As[2 * BM * BK];   // 32KB dbuf
    __shared__ __align__(16) short Bs[2 * BN * BK];   // 32KB dbuf

    int raw = blockIdx.x;
    int sb  = (raw & 7) * 256 + (raw >> 3);
    int ot = sb & 1;
    int xt = (sb >> 1) & 255;
    int b  = sb >> 9;
    int o0 = ot * BM, x0 = xt * BN;

    int t = threadIdx.x;
    int wave = t >> 6, lane = t & 63;
    int wr = wave >> 1, wc = wave & 1;
    int lrow = lane & 15, lk = lane >> 4;
    int lr8 = lane >> 3;
    int aq  = (lane & 7) ^ lr8;

    const unsigned short* asrc = Amat + ((size_t)b * NC + o0) * KTOT
                                 + (size_t)(wave * 32 + lr8) * KTOT + aq * 8;
    const unsigned short* bsrc = Bt + ((size_t)b * 256 + xt) * 16 * 8192
                                 + (size_t)(wave * 32 + lr8) * 64 + aq * 8;

    f32x4 acc[4][4];
    #pragma unroll
    for (int mi = 0; mi < 4; ++mi)
        #pragma unroll
        for (int ni = 0; ni < 4; ++ni)
            acc[mi][ni] = (f32x4){0.f, 0.f, 0.f, 0.f};

    // ---- prologue: issue tile 0 into buf0 (8 vmem per wave) ----
    #pragma unroll
    for (int p = 0; p < 4; ++p)
        __builtin_amdgcn_global_load_lds(
            (const __attribute__((address_space(1))) unsigned int*)
                (asrc + (size_t)p * 8 * KTOT),
            (__attribute__((address_space(3))) unsigned int*)
                (As + (wave * 32 + p * 8) * 64), 16, 0, 0);
    #pragma unroll
    for (int p = 0; p < 4; ++p)
        __builtin_amdgcn_global_load_lds(
            (const __attribute__((address_space(1))) unsigned int*)
                (bsrc + (size_t)p * 8 * 64),
            (__attribute__((address_space(3))) unsigned int*)
                (Bs + (wave * 32 + p * 8) * 64), 16, 0, 0);
    __builtin_amdgcn_sched_barrier(0);

    #pragma unroll 1
    for (int it = 0; it < 16; ++it) {
        // ---- issue next tile -> buf^1 (8 vmem; last iter re-issues 15) ----
        int ja = (it < 15) ? it + 1 : 15;
        int bo = ((it + 1) & 1) * (BM * BK);
        #pragma unroll
        for (int p = 0; p < 4; ++p)
            __builtin_amdgcn_global_load_lds(
                (const __attribute__((address_space(1))) unsigned int*)
                    (asrc + (size_t)p * 8 * KTOT + ja * BK),
                (__attribute__((address_space(3))) unsigned int*)
                    (As + bo + (wave * 32 + p * 8) * 64), 16, 0, 0);
        #pragma unroll
        for (int p = 0; p < 4; ++p)
            __builtin_amdgcn_global_load_lds(
                (const __attribute__((address_space(1))) unsigned int*)
                    (bsrc + (size_t)ja * 8192 + p * 8 * 64),
                (__attribute__((address_space(3))) unsigned int*)
                    (Bs + bo + (wave * 32 + p * 8) * 64), 16, 0, 0);
        __builtin_amdgcn_sched_barrier(0);

        // ---- current tile's 8 loads landed (8 newer in flight) ----
        asm volatile("s_waitcnt vmcnt(8)" ::: "memory");
        __builtin_amdgcn_s_barrier();
        __builtin_amdgcn_sched_barrier(0);

        // ---- compute on buf cur ----
        const short* Acur = As + (it & 1) * (BM * BK);
        const short* Bcur = Bs + (it & 1) * (BM * BK);
        #pragma unroll
        for (int kk = 0; kk < 2; ++kk) {
            int q = kk * 4 + lk;
            short8 af[4], bf[4];
            #pragma unroll
            for (int mi = 0; mi < 4; ++mi)
                af[mi] = *(const short8*)(&Acur[swzA(wr * 64 + mi * 16 + lrow, q)]);
            #pragma unroll
            for (int ni = 0; ni < 4; ++ni)
                bf[ni] = *(const short8*)(&Bcur[swzA(wc * 64 + ni * 16 + lrow, q)]);
            __builtin_amdgcn_s_setprio(1);
            #pragma unroll
            for (int mi = 0; mi < 4; ++mi)
                #pragma unroll
                for (int ni = 0; ni < 4; ++ni)
                    acc[mi][ni] = __builtin_amdgcn_mfma_f32_16x16x32_bf16(
                        af[mi], bf[ni], acc[mi][ni], 0, 0, 0);
            __builtin_amdgcn_s_setprio(0);
        }
        // ---- all waves done reading buf cur (next iter overwrites it) ----
        __builtin_amdgcn_s_barrier();
        __builtin_amdgcn_sched_barrier(0);
    }

    // ---- epilogue ----
    const float* beff_b = beff + b * NC + o0;
    float* outb = out + ((size_t)b * NC + o0) * DWH + x0;
    #pragma unroll
    for (int mi = 0; mi < 4; ++mi) {
        #pragma unroll
        for (int r4 = 0; r4 < 4; ++r4) {
            int row = wr * 64 + mi * 16 + lk * 4 + r4;
            float bias = beff_b[row];
            float* orow = outb + (size_t)row * DWH;
            #pragma unroll
            for (int ni = 0; ni < 4; ++ni) {
                int col = wc * 64 + ni * 16 + lrow;
                orow[col] = acc[mi][ni][r4] + bias;
            }
        }
    }
}

// ===========================================================================
// FALLBACK K3: R12 gemm (fp32 B reg-staged + cvt_pk).
// ===========================================================================
__global__ __launch_bounds__(256, 3) void gemm_kernel(
    const float* __restrict__ i0, const float* __restrict__ i1,
    const float* __restrict__ i2, const float* __restrict__ i3,
    const unsigned short* __restrict__ Amat,
    const float* __restrict__ beff,
    float* __restrict__ out)
{
    __shared__ __align__(16) short As[2 * BM * BK];
    __shared__ __align__(16) short Bs[BN * BK];

    int raw = blockIdx.x;
    int sb  = (raw & 7) * 256 + (raw >> 3);
    int ot = sb & 1;
    int xt = (sb >> 1) & 255;
    int b  = sb >> 9;
    int o0 = ot * BM, x0 = xt * BN;

    const unsigned short* Ab = Amat + ((size_t)b * NC + o0) * KTOT;

    int t = threadIdx.x;
    int wave = t >> 6, lane = t & 63;
    int wr = wave >> 1, wc = wave & 1;
    int lrow = lane & 15, lk = lane >> 4;

    f32x4 acc[4][4];
    #pragma unroll
    for (int mi = 0; mi < 4; ++mi)
        #pragma unroll
        for (int ni = 0; ni < 4; ++ni)
            acc[mi][ni] = (f32x4){0.f, 0.f, 0.f, 0.f};

    int xq = t & 31;
    int kb = (t >> 5) * 8;

    int ar = wave * 32 + (lane >> 3);
    int aq = (lane & 7) ^ (lane >> 3);
    const unsigned short* asrc = Ab + (size_t)ar * KTOT + aq * 8;

    float4 v[8];

    {
        #pragma unroll
        for (int p = 0; p < 4; ++p)
            __builtin_amdgcn_global_load_lds(
                (const __attribute__((address_space(1))) unsigned int*)
                    (asrc + (size_t)p * 8 * KTOT),
                (__attribute__((address_space(3))) unsigned int*)
                    (As + (wave * 32 + p * 8) * 64), 16, 0, 0);
        const float* Bb = i0 + (size_t)b * NC * DWH + x0;
        #pragma unroll
        for (int j = 0; j < 8; ++j)
            v[j] = *(const float4*)(Bb + (size_t)(kb + j) * DWH + xq * 4);
    }

    #pragma unroll 1
    for (int it = 0; it < KTOT / BK; ++it) {
        const short* Acur = As + (it & 1) * (BM * BK);
        short* Anx = As + ((it + 1) & 1) * (BM * BK);

        __builtin_amdgcn_s_barrier();
        __builtin_amdgcn_sched_barrier(0);

        {
            int ja = (it + 1 < 16) ? it + 1 : 15;
            #pragma unroll
            for (int p = 0; p < 4; ++p)
                __builtin_amdgcn_global_load_lds(
                    (const __attribute__((address_space(1))) unsigned int*)
                        (asrc + (size_t)p * 8 * KTOT + ja * BK),
                    (__attribute__((address_space(3))) unsigned int*)
                        (Anx + (wave * 32 + p * 8) * 64), 16, 0, 0);
        }
        __builtin_amdgcn_sched_barrier(0);

        uint4 pk[4];
        #pragma unroll
        for (int i = 0; i < 4; ++i) {
            unsigned w[4];
            #pragma unroll
            for (int j = 0; j < 4; ++j)
                w[j] = pack_bf16x2(((const float*)&v[2 * j])[i],
                                   ((const float*)&v[2 * j + 1])[i]);
            pk[i] = (uint4){w[0], w[1], w[2], w[3]};
        }

        {
            int itn = (it < 15) ? it + 1 : 15;
            int m = itn >> 2, cbase = (itn & 3) * 64;
            const float* Bb = (m == 0 ? i0 : m == 1 ? i1 : m == 2 ? i2 : i3)
                              + ((size_t)b * NC + cbase) * DWH + x0;
            #pragma unroll
            for (int j = 0; j < 8; ++j)
                v[j] = *(const float4*)(Bb + (size_t)(kb + j) * DWH + xq * 4);
        }
        __builtin_amdgcn_sched_barrier(0);

        #pragma unroll
        for (int i = 0; i < 4; ++i)
            *(uint4*)(&Bs[swzB(xq * 4 + i, t >> 5)]) = pk[i];

        asm volatile("s_waitcnt vmcnt(12) lgkmcnt(0)" ::: "memory");
        __builtin_amdgcn_s_barrier();
        __builtin_amdgcn_sched_barrier(0);

        #pragma unroll
        for (int kk = 0; kk < 2; ++kk) {
            int q = kk * 4 + lk;
            short8 af[4], bf[4];
            #pragma unroll
            for (int mi = 0; mi < 4; ++mi)
                af[mi] = *(const short8*)(&Acur[swzA(wr * 64 + mi * 16 + lrow, q)]);
            #pragma unroll
            for (int ni = 0; ni < 4; ++ni)
                bf[ni] = *(const short8*)(&Bs[swzB(wc * 64 + ni * 16 + lrow, q)]);
            __builtin_amdgcn_s_setprio(1);
            #pragma unroll
            for (int mi = 0; mi < 4; ++mi)
                #pragma unroll
                for (int ni = 0; ni < 4; ++ni)
                    acc[mi][ni] = __builtin_amdgcn_mfma_f32_16x16x32_bf16(
                        af[mi], bf[ni], acc[mi][ni], 0, 0, 0);
            __builtin_amdgcn_s_setprio(0);
        }
    }

    const float* beff_b = beff + b * NC + o0;
    float* outb = out + ((size_t)b * NC + o0) * DWH + x0;
    #pragma unroll
    for (int mi = 0; mi < 4; ++mi) {
        #pragma unroll
        for (int r4 = 0; r4 < 4; ++r4) {
            int row = wr * 64 + mi * 16 + lk * 4 + r4;
            float bias = beff_b[row];
            float* orow = outb + (size_t)row * DWH;
            #pragma unroll
            for (int ni = 0; ni < 4; ++ni) {
                int col = wc * 64 + ni * 16 + lrow;
                orow[col] = acc[mi][ni][r4] + bias;
            }
        }
    }
}

// ---------------------------------------------------------------------------
extern "C" void kernel_launch(void* const* d_in, const int* in_sizes, int n_in,
                              void* d_out, int out_size, void* d_ws, size_t ws_size,
                              hipStream_t stream) {
    const float* m1 = (const float*)d_in[0];
    const float* m2 = (const float*)d_in[1];
    const float* m3 = (const float*)d_in[2];
    const float* m4 = (const float*)d_in[3];
    const float* Wq = (const float*)d_in[4];
    const float* bq = (const float*)d_in[5];
    const float* Wk = (const float*)d_in[6];
    const float* bk = (const float*)d_in[7];
    const float* Wc = (const float*)d_in[8];
    const float* bcv = (const float*)d_in[9];
    float* out = (float*)d_out;

    const size_t BT_BYTES = (size_t)NB * KTOT * DWH * 2;   // 256 MB
    const size_t NEED = BT_BYTES + 524288 + 2097152 + 4096;

    if (ws_size >= NEED) {
        // transcode+pool -> attn -> all-bf16 gemm
        unsigned short* Btr   = (unsigned short*)d_ws;
        float* pooled         = (float*)((char*)d_ws + BT_BYTES);
        unsigned short* Amat  = (unsigned short*)((char*)d_ws + BT_BYTES + 524288);
        float* beff           = (float*)((char*)d_ws + BT_BYTES + 524288 + 2097152);

        transpool_kernel<<<2048, 256, 0, stream>>>(m1, m2, m3, m4, Btr, pooled);
        attn_kernel<<<NB * NC, 64, 0, stream>>>(pooled, Wq, bq, Wk, bk, Wc, bcv,
                                                Amat, beff);
        gemm2_kernel<<<2048, 256, 0, stream>>>(Amat, Btr, beff, out);
    } else {
        // FALLBACK: measured R12 path
        float* pooled        = (float*)d_ws;
        unsigned short* Amat = (unsigned short*)((char*)d_ws + 524288);
        float* beff          = (float*)((char*)d_ws + 524288 + 2097152);

        pool_kernel<<<NB * NC * 4, 256, 0, stream>>>(m1, m2, m3, m4, pooled);
        attn_kernel<<<NB * NC, 64, 0, stream>>>(pooled, Wq, bq, Wk, bk, Wc, bcv,
                                                Amat, beff);
        gemm_kernel<<<(NB) * (NC / BM) * (DWH / BN), 256, 0, stream>>>(
            m1, m2, m3, m4, Amat, beff, out);
    }
}